// Round 5
// baseline (1626.305 us; speedup 1.0000x reference)
//
#include <hip/hip_runtime.h>
#include <hip/hip_bf16.h>
#include <float.h>

// Problem constants
#define BQ 512     // batch
#define LQ 12      // L
#define DQ 768     // D
#define TQ 20      // tasks
#define NKQ 100    // keys per task
#define NPQ 10     // prompts per task
#define NKEY (TQ*NKQ)   // 2000 keys per l

// argmin kernel tiling: lane = key, SGPR-broadcast X, no LDS
#define NKSET 32   // 32 key-sets of 64 (2048, last 48 lanes masked)
#define NB 64      // b per block
#define DT 32      // d per chunk
#define NCHD (DQ/DT)  // 24

// ---------------- K2: per-(l, b-set, key-set) partial argmin ----------------
// One wave per block. Lane holds one key's d-chunk in VGPRs; X rows arrive as
// wave-uniform scalar loads (SGPR operand of v_fmac_f32). k2 computed inline.
__global__ __launch_bounds__(64)
void argmin_kernel(const float* __restrict__ xq, const float* __restrict__ keys,
                   float* __restrict__ pval, int* __restrict__ pidx) {
    const int kset = blockIdx.x;        // 0..31
    const int bset = blockIdx.y;        // 0..7
    const int l    = blockIdx.z;        // 0..11
    const int lane = threadIdx.x;       // 0..63
    const int g    = kset * 64 + lane;  // global key id
    const int gc   = g < NKEY ? g : NKEY - 1;   // clamped for loads
    const int b0   = bset * NB;

    const float* __restrict__ krow  = keys + ((size_t)l * NKEY + gc) * DQ;
    const float* __restrict__ xbase = xq + ((size_t)b0 * LQ + l) * DQ;

    float acc[NB];
#pragma unroll
    for (int i = 0; i < NB; ++i) acc[i] = 0.f;
    float k2 = 0.f;

#pragma unroll 1
    for (int dc = 0; dc < NCHD; ++dc) {     // 24 d-chunks, kept as a loop (I$)
        const int d0 = dc * DT;
        // per-lane K fragment: 2 cache lines (128 B), 8x dwordx4 gather
        float kf[DT];
#pragma unroll
        for (int q = 0; q < DT / 4; ++q) {
            float4 v = *reinterpret_cast<const float4*>(krow + d0 + q * 4);
            kf[q * 4 + 0] = v.x; kf[q * 4 + 1] = v.y;
            kf[q * 4 + 2] = v.z; kf[q * 4 + 3] = v.w;
        }
        // inline k2 accumulation (replaces the separate k2 kernel)
#pragma unroll
        for (int d = 0; d < DT; ++d) k2 = fmaf(kf[d], kf[d], k2);
        // 64 b's; X chunk is wave-uniform -> s_load, SGPR operand in FMA
#pragma unroll
        for (int bi = 0; bi < NB; ++bi) {
            const float* __restrict__ xrow = xbase + (size_t)bi * (LQ * DQ) + d0;
#pragma unroll
            for (int d = 0; d < DT; ++d)
                acc[bi] = fmaf(kf[d], xrow[d], acc[bi]);
        }
    }

    // epilogue: score = k2 - 2*dot (q2 dropped: constant over argmin axis).
    // Per b: 64-lane butterfly argmin, tie -> smaller global key idx.
    const bool valid = (g < NKEY);
#pragma unroll
    for (int bi = 0; bi < NB; ++bi) {
        float v  = valid ? fmaf(-2.f, acc[bi], k2) : FLT_MAX;
        int  idx = g;
#pragma unroll
        for (int m = 1; m < 64; m <<= 1) {
            float ov = __shfl_xor(v, m, 64);
            int   oi = __shfl_xor(idx, m, 64);
            if (ov < v || (ov == v && oi < idx)) { v = ov; idx = oi; }
        }
        if (lane == bi) {   // all lanes hold the result; lane bi stores b0+bi
            size_t o = ((size_t)l * BQ + b0 + bi) * NKSET + kset;
            pval[o] = v;
            pidx[o] = idx;
        }
    }
}

// ---------------- K3: combine partials + gather prompts ----------------
__global__ __launch_bounds__(256)
void gather_kernel(const float* __restrict__ prompts,
                   const float* __restrict__ pval, const int* __restrict__ pidx,
                   float* __restrict__ out) {
    const int b = blockIdx.x;   // 0..511
    const int l = blockIdx.y;   // 0..11
    size_t base = ((size_t)l * BQ + b) * NKSET;
    float bv = FLT_MAX; int bi = 0x7fffffff;
#pragma unroll
    for (int c = 0; c < NKSET; ++c) {
        float v = pval[base + c]; int idx = pidx[base + c];
        if (v < bv || (v == bv && idx < bi)) { bv = v; bi = idx; }
    }
    int task = bi / NKQ;
    const float4* src = reinterpret_cast<const float4*>(
        prompts + ((size_t)l * TQ + task) * (NPQ * DQ));
    float4* dst = reinterpret_cast<float4*>(
        out + ((size_t)l * BQ + b) * (size_t)(NPQ * DQ));
    const int n4 = NPQ * DQ / 4;  // 1920
    for (int i = threadIdx.x; i < n4; i += blockDim.x) dst[i] = src[i];
    if (b == 0 && l == 0 && threadIdx.x == 0)
        out[(size_t)LQ * BQ * NPQ * DQ] = 0.0f;   // trailing scalar output (0.0)
}

extern "C" void kernel_launch(void* const* d_in, const int* in_sizes, int n_in,
                              void* d_out, int out_size, void* d_ws, size_t ws_size,
                              hipStream_t stream) {
    const float* xq      = (const float*)d_in[0];  // (B,L,D)
    const float* keys    = (const float*)d_in[1];  // (L,T,NK,D)
    const float* prompts = (const float*)d_in[2];  // (L,T,NP,D)
    float* out = (float*)d_out;

    // workspace: pval float[12*512*32] then pidx int[12*512*32]  (~1.57 MB)
    float* pval = (float*)d_ws;
    int*   pidx = (int*)((float*)d_ws + (size_t)LQ * BQ * NKSET);

    hipLaunchKernelGGL(argmin_kernel, dim3(NKSET, BQ / NB, LQ), dim3(64), 0, stream,
                       xq, keys, pval, pidx);
    hipLaunchKernelGGL(gather_kernel, dim3(BQ, LQ), dim3(256), 0, stream,
                       prompts, pval, pidx, out);
}

// Round 6
// 417.594 us; speedup vs baseline: 3.8945x; 3.8945x over previous
//
#include <hip/hip_runtime.h>
#include <hip/hip_bf16.h>
#include <float.h>

// Problem constants
#define BQ 512
#define LQ 12
#define DQ 768
#define TQ 20
#define NKQ 100
#define NPQ 10
#define NKEY 2000
#define KPAD 2048
#define MARGIN 8.0f   // >> worst-case bf16 dot error (~2.4)

typedef __attribute__((ext_vector_type(8))) short short8v;  // 8 bf16 (4 VGPR)
typedef __attribute__((ext_vector_type(4))) float f32x4;

__device__ __forceinline__ ushort f2bf(float f) {
    __hip_bfloat16 h = __float2bfloat16(f);
    return *reinterpret_cast<ushort*>(&h);
}

// ---------------- K1a: keys f32 -> bf16, plus exact f32 k2 ----------------
__global__ __launch_bounds__(256)
void cvt_keys_kernel(const float* __restrict__ keys, ushort* __restrict__ kb,
                     float* __restrict__ k2) {
    int wave = threadIdx.x >> 6, lane = threadIdx.x & 63;
    int row = blockIdx.x * 4 + wave;            // 0..23999 (l*2000+g)
    const float* kp = keys + (size_t)row * DQ;
    ushort* op = kb + (size_t)row * DQ;
    float s = 0.f;
#pragma unroll
    for (int c = 0; c < 3; ++c) {
        float4 v = *reinterpret_cast<const float4*>(kp + c * 256 + lane * 4);
        s = fmaf(v.x, v.x, s); s = fmaf(v.y, v.y, s);
        s = fmaf(v.z, v.z, s); s = fmaf(v.w, v.w, s);
        ushort4 o = make_ushort4(f2bf(v.x), f2bf(v.y), f2bf(v.z), f2bf(v.w));
        *reinterpret_cast<ushort4*>(op + c * 256 + lane * 4) = o;
    }
#pragma unroll
    for (int m = 32; m; m >>= 1) s += __shfl_xor(s, m, 64);
    if (lane == 0) k2[row] = s;
}

// ---------------- K1b: x f32 -> bf16 ----------------
__global__ __launch_bounds__(256)
void cvt_x_kernel(const float* __restrict__ x, ushort* __restrict__ xb) {
    size_t i = (size_t)blockIdx.x * 256 + threadIdx.x;   // float4 index, exact cover
    float4 v = reinterpret_cast<const float4*>(x)[i];
    ushort4 o = make_ushort4(f2bf(v.x), f2bf(v.y), f2bf(v.z), f2bf(v.w));
    reinterpret_cast<ushort4*>(xb)[i] = o;
}

// ---------------- K2: MFMA bf16 approx scores ----------------
// Block: 64 b x 128 keys, 4 waves (each 32b x 64k = 2x4 16x16 tiles).
// Both operands row-major [row][d] (B^T GEMM form); frag: row=lane&15,
// k-base=(lane>>4)*8; C/D: col=lane&15, row=(lane>>4)*4+reg (m89/m92-verified).
__global__ __launch_bounds__(256)
void score_kernel(const ushort* __restrict__ xb, const ushort* __restrict__ kb,
                  const float* __restrict__ k2, float* __restrict__ scores) {
    const int bset = blockIdx.x;   // 0..7
    const int kset = blockIdx.y;   // 0..15
    const int l    = blockIdx.z;   // 0..11
    const int b0 = bset * 64, k0 = kset * 128;
    const int tid = threadIdx.x, lane = tid & 63, w = tid >> 6;
    const int wm0 = (w & 1) * 2, wn0 = (w >> 1) * 4;
    const int lr = lane & 15, ls = lane >> 4;

    // rows padded to 40 shorts (80 B): frag reads <=2-way bank alias (free)
    __shared__ ushort XL[64 * 40];
    __shared__ ushort KL[128 * 40];

    f32x4 acc[2][4];
#pragma unroll
    for (int m = 0; m < 2; ++m)
#pragma unroll
        for (int n = 0; n < 4; ++n) acc[m][n] = (f32x4){0.f, 0.f, 0.f, 0.f};

    const int row = tid >> 2, slot = tid & 3;  // 16B stores: 64/128 rows x 4 slots
    int g1 = k0 + row;       if (g1 > NKEY - 1) g1 = NKEY - 1;
    int g2 = k0 + row + 64;  if (g2 > NKEY - 1) g2 = NKEY - 1;
    const ushort* xsrc = xb + ((size_t)(b0 + row) * LQ + l) * DQ + slot * 8;
    const ushort* ksrc1 = kb + ((size_t)l * NKEY + g1) * DQ + slot * 8;
    const ushort* ksrc2 = kb + ((size_t)l * NKEY + g2) * DQ + slot * 8;

    for (int dc = 0; dc < DQ / 32; ++dc) {     // 24 K-steps of 32
        *reinterpret_cast<short8v*>(&XL[row * 40 + slot * 8]) =
            *reinterpret_cast<const short8v*>(xsrc + dc * 32);
        *reinterpret_cast<short8v*>(&KL[row * 40 + slot * 8]) =
            *reinterpret_cast<const short8v*>(ksrc1 + dc * 32);
        *reinterpret_cast<short8v*>(&KL[(row + 64) * 40 + slot * 8]) =
            *reinterpret_cast<const short8v*>(ksrc2 + dc * 32);
        __syncthreads();
        short8v a[2], bf[4];
#pragma unroll
        for (int m = 0; m < 2; ++m)
            a[m] = *reinterpret_cast<const short8v*>(
                &XL[((wm0 + m) * 16 + lr) * 40 + ls * 8]);
#pragma unroll
        for (int n = 0; n < 4; ++n)
            bf[n] = *reinterpret_cast<const short8v*>(
                &KL[((wn0 + n) * 16 + lr) * 40 + ls * 8]);
#pragma unroll
        for (int m = 0; m < 2; ++m)
#pragma unroll
            for (int n = 0; n < 4; ++n)
                acc[m][n] = __builtin_amdgcn_mfma_f32_16x16x32_bf16(
                    a[m], bf[n], acc[m][n], 0, 0, 0);
        __syncthreads();
    }

    // epilogue: score = k2 - 2*dot; sentinel FLT_MAX for padded keys
#pragma unroll
    for (int m = 0; m < 2; ++m)
#pragma unroll
        for (int n = 0; n < 4; ++n) {
            int g = k0 + (wn0 + n) * 16 + lr;
            float kk = (g < NKEY) ? k2[l * NKEY + g] : 0.f;
#pragma unroll
            for (int r = 0; r < 4; ++r) {
                int b = b0 + (wm0 + m) * 16 + ls * 4 + r;
                float val = (g < NKEY) ? fmaf(-2.f, acc[m][n][r], kk) : FLT_MAX;
                scores[((size_t)l * BQ + b) * KPAD + g] = val;
            }
        }
}

// ---------------- K3: block-min + exact rescore + fused gather ----------------
__global__ __launch_bounds__(256)
void finalize_kernel(const float* __restrict__ x, const float* __restrict__ keys,
                     const float* __restrict__ k2, const float* __restrict__ scores,
                     const float* __restrict__ prompts, float* __restrict__ out) {
    const int b = blockIdx.x, l = blockIdx.y;
    const int tid = threadIdx.x, lane = tid & 63, w = tid >> 6;
    const float* sc = scores + ((size_t)l * BQ + b) * KPAD;
    __shared__ float wred[4];
    __shared__ int   wredi[4];
    __shared__ int   s_task;

    float4 v0 = reinterpret_cast<const float4*>(sc)[tid];        // g = 4*tid..
    float4 v1 = reinterpret_cast<const float4*>(sc)[tid + 256];  // g = 1024+4*tid..
    float m = fminf(fminf(fminf(v0.x, v0.y), fminf(v0.z, v0.w)),
                    fminf(fminf(v1.x, v1.y), fminf(v1.z, v1.w)));
#pragma unroll
    for (int s = 32; s; s >>= 1) m = fminf(m, __shfl_xor(m, s, 64));
    if (lane == 0) wred[w] = m;
    __syncthreads();
    float mt = fminf(fminf(wred[0], wred[1]), fminf(wred[2], wred[3])) + MARGIN;
    __syncthreads();   // protect wred reuse below

    // exact rescore of candidates (expected ~1-2 per block)
    float bv = FLT_MAX; int bg = 0x7fffffff;
    float cand[8] = {v0.x, v0.y, v0.z, v0.w, v1.x, v1.y, v1.z, v1.w};
    const float* xrow = x + ((size_t)b * LQ + l) * DQ;
#pragma unroll
    for (int j = 0; j < 8; ++j) {
        int g = (j < 4) ? tid * 4 + j : 1024 + tid * 4 + (j - 4);
        if (cand[j] <= mt && g < NKEY) {
            const float* krow = keys + ((size_t)l * NKEY + g) * DQ;
            float dot = 0.f;
            for (int i = 0; i < DQ / 4; ++i) {
                float4 xv = reinterpret_cast<const float4*>(xrow)[i];
                float4 kv = reinterpret_cast<const float4*>(krow)[i];
                dot = fmaf(xv.x, kv.x, dot); dot = fmaf(xv.y, kv.y, dot);
                dot = fmaf(xv.z, kv.z, dot); dot = fmaf(xv.w, kv.w, dot);
            }
            float ex = fmaf(-2.f, dot, k2[l * NKEY + g]);
            if (ex < bv || (ex == bv && g < bg)) { bv = ex; bg = g; }
        }
    }
    // block argmin, tie -> smaller g
#pragma unroll
    for (int s = 1; s < 64; s <<= 1) {
        float ov = __shfl_xor(bv, s, 64); int og = __shfl_xor(bg, s, 64);
        if (ov < bv || (ov == bv && og < bg)) { bv = ov; bg = og; }
    }
    if (lane == 0) { wred[w] = bv; wredi[w] = bg; }
    __syncthreads();
    if (tid == 0) {
        float fv = wred[0]; int fg = wredi[0];
#pragma unroll
        for (int c = 1; c < 4; ++c)
            if (wred[c] < fv || (wred[c] == fv && wredi[c] < fg)) { fv = wred[c]; fg = wredi[c]; }
        s_task = fg / NKQ;
    }
    __syncthreads();
    int task = s_task;
    const float4* src = reinterpret_cast<const float4*>(
        prompts + ((size_t)l * TQ + task) * (NPQ * DQ));
    float4* dst = reinterpret_cast<float4*>(
        out + ((size_t)l * BQ + b) * (size_t)(NPQ * DQ));
    for (int i = tid; i < NPQ * DQ / 4; i += 256) dst[i] = src[i];
    if (b == 0 && l == 0 && tid == 0)
        out[(size_t)LQ * BQ * NPQ * DQ] = 0.0f;   // trailing scalar output
}

// ---------------- Fallback (small ws): R3 correct-but-slow path ----------------
#define NKSET 32
#define NB 64
__global__ __launch_bounds__(64)
void fb_argmin(const float* __restrict__ xq, const float* __restrict__ keys,
               float* __restrict__ pval, int* __restrict__ pidx) {
    const int kset = blockIdx.x, bset = blockIdx.y, l = blockIdx.z;
    const int lane = threadIdx.x;
    const int g = kset * 64 + lane;
    const int gc = g < NKEY ? g : NKEY - 1;
    const int b0 = bset * NB;
    const float* krow  = keys + ((size_t)l * NKEY + gc) * DQ;
    const float* xbase = xq + ((size_t)b0 * LQ + l) * DQ;
    float acc[NB];
#pragma unroll
    for (int i = 0; i < NB; ++i) acc[i] = 0.f;
    float k2v = 0.f;
#pragma unroll 1
    for (int dc = 0; dc < DQ / 32; ++dc) {
        const int d0 = dc * 32;
        float kf[32];
#pragma unroll
        for (int q = 0; q < 8; ++q) {
            float4 v = *reinterpret_cast<const float4*>(krow + d0 + q * 4);
            kf[q*4+0]=v.x; kf[q*4+1]=v.y; kf[q*4+2]=v.z; kf[q*4+3]=v.w;
        }
#pragma unroll
        for (int d = 0; d < 32; ++d) k2v = fmaf(kf[d], kf[d], k2v);
#pragma unroll
        for (int bi = 0; bi < NB; ++bi) {
            const float* xrow = xbase + (size_t)bi * (LQ * DQ) + d0;
#pragma unroll
            for (int d = 0; d < 32; ++d) acc[bi] = fmaf(kf[d], xrow[d], acc[bi]);
        }
    }
    const bool valid = (g < NKEY);
#pragma unroll
    for (int bi = 0; bi < NB; ++bi) {
        float v = valid ? fmaf(-2.f, acc[bi], k2v) : FLT_MAX;
        int idx = g;
#pragma unroll
        for (int m = 1; m < 64; m <<= 1) {
            float ov = __shfl_xor(v, m, 64);
            int   oi = __shfl_xor(idx, m, 64);
            if (ov < v || (ov == v && oi < idx)) { v = ov; idx = oi; }
        }
        if (lane == bi) {
            size_t o = ((size_t)l * BQ + b0 + bi) * NKSET + kset;
            pval[o] = v; pidx[o] = idx;
        }
    }
}

__global__ __launch_bounds__(256)
void fb_gather(const float* __restrict__ prompts,
               const float* __restrict__ pval, const int* __restrict__ pidx,
               float* __restrict__ out) {
    const int b = blockIdx.x, l = blockIdx.y;
    size_t base = ((size_t)l * BQ + b) * NKSET;
    float bv = FLT_MAX; int bi = 0x7fffffff;
#pragma unroll
    for (int c = 0; c < NKSET; ++c) {
        float v = pval[base + c]; int idx = pidx[base + c];
        if (v < bv || (v == bv && idx < bi)) { bv = v; bi = idx; }
    }
    int task = bi / NKQ;
    const float4* src = reinterpret_cast<const float4*>(
        prompts + ((size_t)l * TQ + task) * (NPQ * DQ));
    float4* dst = reinterpret_cast<float4*>(
        out + ((size_t)l * BQ + b) * (size_t)(NPQ * DQ));
    for (int i = threadIdx.x; i < NPQ * DQ / 4; i += blockDim.x) dst[i] = src[i];
    if (b == 0 && l == 0 && threadIdx.x == 0)
        out[(size_t)LQ * BQ * NPQ * DQ] = 0.0f;
}

extern "C" void kernel_launch(void* const* d_in, const int* in_sizes, int n_in,
                              void* d_out, int out_size, void* d_ws, size_t ws_size,
                              hipStream_t stream) {
    const float* xq      = (const float*)d_in[0];  // (B,L,D)
    const float* keys    = (const float*)d_in[1];  // (L,T,NK,D)
    const float* prompts = (const float*)d_in[2];  // (L,T,NP,D)
    float* out = (float*)d_out;

    // fast-path ws layout (bytes):
    //   [0, 36864000)          keys_bf16  (12*2000*768 ushort)
    //   [36864000, 46301184)   x_bf16     (512*12*768 ushort)
    //   [46301184, 46397184)   k2         (24000 f32)
    //   [46397184, 96728832)   scores     (12*512*2048 f32)
    const size_t NEED = 96728832ULL;
    char* ws = (char*)d_ws;
    if (ws_size >= NEED) {
        ushort* kb = (ushort*)(ws);
        ushort* xb = (ushort*)(ws + 36864000ULL);
        float*  k2 = (float*)(ws + 46301184ULL);
        float*  sc = (float*)(ws + 46397184ULL);
        hipLaunchKernelGGL(cvt_keys_kernel, dim3(6000), dim3(256), 0, stream, keys, kb, k2);
        hipLaunchKernelGGL(cvt_x_kernel, dim3(4608), dim3(256), 0, stream, xq, xb);
        hipLaunchKernelGGL(score_kernel, dim3(8, 16, 12), dim3(256), 0, stream,
                           xb, kb, k2, sc);
        hipLaunchKernelGGL(finalize_kernel, dim3(BQ, LQ), dim3(256), 0, stream,
                           xq, keys, k2, sc, prompts, out);
    } else {
        float* pval = (float*)d_ws;
        int*   pidx = (int*)((float*)d_ws + (size_t)LQ * BQ * NKSET);
        hipLaunchKernelGGL(fb_argmin, dim3(NKSET, BQ / NB, LQ), dim3(64), 0, stream,
                           xq, keys, pval, pidx);
        hipLaunchKernelGGL(fb_gather, dim3(BQ, LQ), dim3(256), 0, stream,
                           prompts, pval, pidx, out);
    }
}